// Round 3
// baseline (134.604 us; speedup 1.0000x reference)
//
#include <hip/hip_runtime.h>
#include <math.h>

#define Bn 32
#define Ln 524288
#define NF 4

#define TPB  512                 // threads per workgroup
#define CHK  32                  // samples per thread
#define TILE (TPB * CHK)         // 16384 samples per tile
#define TPR  (Ln / TILE)         // 32 tiles per row
#define NT   (Bn * TPR)          // 1024 tiles

// ws layout (float indices)
#define COEF_OFF 0               // 20 floats
#define POW_OFF  64              // 9 mats A^(32*2^j), j=0..8   [64, 640)
#define LB_OFF   640             // 32 mats K^m, m=0..31 (K=A^16384) [640, 2688)
#define AGG_OFF  2688            // NT*8 tile aggregates [2688, 10880)
#define FLAG_I   10880           // NT ints
#define CNT_I    11904           // 1 int

// LDS layout (float indices within the 64KB block)
#define SCAN_LDS 0               // 512 * 9 = 4608 (padded stride 9, bank-clean)
#define MA_LDS   4608            // 9*64 POW + 32*64 LB = 2624 floats
#define LBM_LDS  (MA_LDS + 576)
#define E_LDS    (MA_LDS + 2624) // 8 floats

// ---------------------------------------------------------------------------
// Kernel 0: reset flags/counter; coefficients (f32-rounded, double math);
// A^32 by unit-state simulation; squaring chain A^(32*2^j) j=0..8 and
// K = A^16384; lookback powers K^m, m=0..31 (P_0 = I). 1 block, 64 threads.
// ---------------------------------------------------------------------------
__global__ void precompute_k(const float* __restrict__ lr,
                             const float* __restrict__ ra,
                             const float* __restrict__ b0,
                             const float* __restrict__ b1,
                             const float* __restrict__ b2,
                             float* __restrict__ ws) {
    __shared__ double Md[64];
    __shared__ double Td[64];
    __shared__ double Pd[64];
    const int t = threadIdx.x;

    // reset lookback flags + tile counter (poison-safe, per-call determinism)
    int* fl = (int*)ws;
    for (int i = t; i < NT; i += 64) fl[FLAG_I + i] = 0;
    if (t == 0) fl[CNT_I] = 0;

    if (t < NF) {
        double r   = 0.999 / (1.0 + exp(-(double)lr[t]));
        double ang = 3.14159265358979323846 / (1.0 + exp(-(double)ra[t]));
        ws[COEF_OFF + t * 5 + 0] = b0[t];
        ws[COEF_OFF + t * 5 + 1] = b1[t];
        ws[COEF_OFF + t * 5 + 2] = b2[t];
        ws[COEF_OFF + t * 5 + 3] = (float)(-2.0 * r * cos(ang));
        ws[COEF_OFF + t * 5 + 4] = (float)(r * r);
    }
    __syncthreads();

    if (t < 8) {
        double cb0[NF], cb1[NF], cb2[NF], ca1[NF], ca2[NF];
        for (int f = 0; f < NF; ++f) {
            cb0[f] = (double)ws[COEF_OFF + f * 5 + 0];
            cb1[f] = (double)ws[COEF_OFF + f * 5 + 1];
            cb2[f] = (double)ws[COEF_OFF + f * 5 + 2];
            ca1[f] = (double)ws[COEF_OFF + f * 5 + 3];
            ca2[f] = (double)ws[COEF_OFF + f * 5 + 4];
        }
        double s[8];
        for (int r = 0; r < 8; ++r) s[r] = 0.0;
        s[t] = 1.0;
        for (int n = 0; n < CHK; ++n) {
            double v = 0.0;
            for (int f = 0; f < NF; ++f) {
                double y     = cb0[f] * v + s[2 * f];
                s[2 * f]     = cb1[f] * v - ca1[f] * y + s[2 * f + 1];
                s[2 * f + 1] = cb2[f] * v - ca2[f] * y;
                v = y;
            }
        }
        for (int r = 0; r < 8; ++r) Md[r * 8 + t] = s[r];  // column t of A^32
    }
    __syncthreads();

    ws[POW_OFF + t] = (float)Md[t];  // j = 0

    const int r8 = t >> 3, c8 = t & 7;
    for (int sq = 1; sq <= 9; ++sq) {
        double acc = 0.0;
        for (int m = 0; m < 8; ++m) acc += Md[r8 * 8 + m] * Md[m * 8 + c8];
        Td[t] = acc;
        __syncthreads();
        Md[t] = Td[t];
        __syncthreads();
        if (sq <= 8) ws[POW_OFF + sq * 64 + t] = (float)Md[t];
    }
    // Md = K = A^16384
    ws[LB_OFF + t] = (r8 == c8) ? 1.f : 0.f;  // P_0 = I
    Pd[t] = Md[t];
    ws[LB_OFF + 64 + t] = (float)Pd[t];       // P_1
    __syncthreads();
    for (int m = 2; m < 32; ++m) {
        double acc = 0.0;
        for (int j = 0; j < 8; ++j) acc += Pd[r8 * 8 + j] * Md[j * 8 + c8];
        Td[t] = acc;
        __syncthreads();
        Pd[t] = Td[t];
        __syncthreads();
        ws[LB_OFF + m * 64 + t] = (float)Pd[t];
    }
}

// ---------------------------------------------------------------------------
__device__ __forceinline__ void step1(float& u, float* s,
                                      const float* c0, const float* c1,
                                      const float* c2, const float* A1,
                                      const float* A2) {
#pragma unroll
    for (int f = 0; f < NF; ++f) {
        float yv     = fmaf(c0[f], u, s[2 * f]);
        s[2 * f]     = fmaf(-A1[f], yv, fmaf(c1[f], u, s[2 * f + 1]));
        s[2 * f + 1] = fmaf(-A2[f], yv, c2[f] * u);
        u = yv;
    }
}

// ---------------------------------------------------------------------------
// Main kernel: single-pass scan with deterministic aggregate-only lookback.
// One WG = one tile of 16384 samples (512 thr x 32 samples).
// ---------------------------------------------------------------------------
__global__ __launch_bounds__(TPB, 4) void biquad_sp_k(const float* __restrict__ x,
                                                      float* __restrict__ ws,
                                                      float* __restrict__ y) {
    __shared__ float4 lds4[4096];  // 64 KB exactly
    float* ldsf = (float*)lds4;
    const int t = threadIdx.x;
    int* flags = (int*)ws + FLAG_I;

    // dynamic tile assignment (scheduling-order => lookback progress safety)
    if (t == 0) ((int*)ldsf)[0] = atomicAdd((int*)ws + CNT_I, 1);
    __syncthreads();
    const int tile = ((int*)ldsf)[0];
    __syncthreads();  // before staging overwrites slot 0
    const int row  = tile / TPR;
    const int tpos = tile % TPR;

    // stage x -> LDS, coalesced global reads, XOR-swizzled slots
    const float4* xg = (const float4*)x + (size_t)row * (Ln / 4) + (size_t)tpos * (TILE / 4);
#pragma unroll
    for (int j = 0; j < TILE / 4 / TPB; ++j) {
        const int n    = j * TPB + t;
        const int slot = (n & ~7) | ((n & 7) ^ ((n >> 3) & 7));
        lds4[slot] = xg[n];
    }

    float c0[NF], c1[NF], c2[NF], A1[NF], A2[NF];
#pragma unroll
    for (int f = 0; f < NF; ++f) {
        c0[f] = ws[COEF_OFF + f * 5 + 0];
        c1[f] = ws[COEF_OFF + f * 5 + 1];
        c2[f] = ws[COEF_OFF + f * 5 + 2];
        A1[f] = ws[COEF_OFF + f * 5 + 3];
        A2[f] = ws[COEF_OFF + f * 5 + 4];
    }
    __syncthreads();

    // LDS -> regs (conflict-free via swizzle)
    float4 xr[CHK / 4];
#pragma unroll
    for (int i = 0; i < CHK / 4; ++i) xr[i] = lds4[t * 8 + (i ^ (t & 7))];
    __syncthreads();  // LDS free for scan + matrices

    // matrices -> LDS (global coalesced, read-broadcast later)
    for (int i = t; i < 2624; i += TPB) ldsf[MA_LDS + i] = ws[64 + i];

    // zero-state pass: per-chunk final state d (outputs discarded)
    float s[8];
#pragma unroll
    for (int r = 0; r < 8; ++r) s[r] = 0.f;
#pragma unroll
    for (int i = 0; i < CHK / 4; ++i) {
        float q[4] = {xr[i].x, xr[i].y, xr[i].z, xr[i].w};
#pragma unroll
        for (int e = 0; e < 4; ++e) { float u = q[e]; step1(u, s, c0, c1, c2, A1, A2); }
    }

#pragma unroll
    for (int r = 0; r < 8; ++r) ldsf[SCAN_LDS + t * 9 + r] = s[r];
    __syncthreads();  // scan init + matrices both visible

    // Kogge-Stone affine scan over 512 chunk states: v_c += A^(32*2^j) * v_{c-2^j}
    float v[8];
#pragma unroll
    for (int r = 0; r < 8; ++r) v[r] = s[r];
    for (int j = 0; j < 9; ++j) {
        const int st = 1 << j;
        float p[8];
        if (t >= st) {
#pragma unroll
            for (int r = 0; r < 8; ++r) p[r] = ldsf[SCAN_LDS + (t - st) * 9 + r];
        }
        __syncthreads();
        if (t >= st) {
            const float* T = ldsf + MA_LDS + j * 64;
#pragma unroll
            for (int r = 0; r < 8; ++r) {
                float acc = v[r];
#pragma unroll
                for (int m = 0; m < 8; ++m) acc = fmaf(T[r * 8 + m], p[m], acc);
                v[r] = acc;
            }
#pragma unroll
            for (int r = 0; r < 8; ++r) ldsf[SCAN_LDS + t * 9 + r] = v[r];
        }
        __syncthreads();
    }

    // publish tile aggregate D = inclusive state of last chunk
    if (t == TPB - 1) {
        float* ag = ws + AGG_OFF + (size_t)tile * 8;
#pragma unroll
        for (int r = 0; r < 8; ++r) ag[r] = v[r];
        __threadfence();
        __hip_atomic_store(&flags[tile], 1, __ATOMIC_RELEASE, __HIP_MEMORY_SCOPE_AGENT);
    }

    // lookback (wave 0): E = sum_{m=0..tpos-1} K^m * D[tile-1-m]  (deterministic)
    if (t < 64) {
        float e8[8];
#pragma unroll
        for (int r = 0; r < 8; ++r) e8[r] = 0.f;
        if (t < tpos) {
            const int pt = tile - 1 - t;
            while (__hip_atomic_load(&flags[pt], __ATOMIC_ACQUIRE,
                                     __HIP_MEMORY_SCOPE_AGENT) == 0) {
                __builtin_amdgcn_s_sleep(4);
            }
            const float* D = ws + AGG_OFF + (size_t)pt * 8;
            float dv[8];
#pragma unroll
            for (int r = 0; r < 8; ++r) dv[r] = D[r];
            const float* P = ldsf + LBM_LDS + t * 64;
#pragma unroll
            for (int r = 0; r < 8; ++r) {
                float acc = 0.f;
#pragma unroll
                for (int m = 0; m < 8; ++m) acc = fmaf(P[r * 8 + m], dv[m], acc);
                e8[r] = acc;
            }
        }
#pragma unroll
        for (int off = 32; off >= 1; off >>= 1) {
#pragma unroll
            for (int r = 0; r < 8; ++r) e8[r] += __shfl_xor(e8[r], off);
        }
        if (t == 0) {
#pragma unroll
            for (int r = 0; r < 8; ++r) ldsf[E_LDS + r] = e8[r];
        }
    }
    __syncthreads();

    // w = A^(32*t) * E via binary decomposition (powers of A commute)
    float w[8];
#pragma unroll
    for (int r = 0; r < 8; ++r) w[r] = ldsf[E_LDS + r];
    for (int j = 0; j < 9; ++j) {
        if (t & (1 << j)) {
            const float* T = ldsf + MA_LDS + j * 64;
            float nw[8];
#pragma unroll
            for (int r = 0; r < 8; ++r) {
                float acc = 0.f;
#pragma unroll
                for (int m = 0; m < 8; ++m) acc = fmaf(T[r * 8 + m], w[m], acc);
                nw[r] = acc;
            }
#pragma unroll
            for (int r = 0; r < 8; ++r) w[r] = nw[r];
        }
    }

    // chunk entry state = w + s_rel(t-1)
#pragma unroll
    for (int r = 0; r < 8; ++r) s[r] = w[r] + ((t > 0) ? ldsf[SCAN_LDS + (t - 1) * 9 + r] : 0.f);
    __syncthreads();  // done reading scan area; LDS free for y

    // final pass from exact entry state, in place xr -> y
#pragma unroll
    for (int i = 0; i < CHK / 4; ++i) {
        float q[4] = {xr[i].x, xr[i].y, xr[i].z, xr[i].w};
#pragma unroll
        for (int e = 0; e < 4; ++e) { float u = q[e]; step1(u, s, c0, c1, c2, A1, A2); q[e] = u; }
        xr[i].x = q[0]; xr[i].y = q[1]; xr[i].z = q[2]; xr[i].w = q[3];
    }

    // y regs -> LDS (swizzled) -> global coalesced
#pragma unroll
    for (int i = 0; i < CHK / 4; ++i) lds4[t * 8 + (i ^ (t & 7))] = xr[i];
    __syncthreads();

    float4* yg = (float4*)y + (size_t)row * (Ln / 4) + (size_t)tpos * (TILE / 4);
#pragma unroll
    for (int j = 0; j < TILE / 4 / TPB; ++j) {
        const int n    = j * TPB + t;
        const int slot = (n & ~7) | ((n & 7) ^ ((n >> 3) & 7));
        yg[n] = lds4[slot];
    }
}

// ---------------------------------------------------------------------------
extern "C" void kernel_launch(void* const* d_in, const int* in_sizes, int n_in,
                              void* d_out, int out_size, void* d_ws, size_t ws_size,
                              hipStream_t stream) {
    const float* x  = (const float*)d_in[0];
    const float* lr = (const float*)d_in[1];
    const float* ra = (const float*)d_in[2];
    const float* b0 = (const float*)d_in[3];
    const float* b1 = (const float*)d_in[4];
    const float* b2 = (const float*)d_in[5];
    float* y  = (float*)d_out;
    float* ws = (float*)d_ws;

    precompute_k<<<dim3(1), dim3(64), 0, stream>>>(lr, ra, b0, b1, b2, ws);
    biquad_sp_k<<<dim3(NT), dim3(TPB), 0, stream>>>(x, ws, y);
}